// Round 6
// baseline (313.816 us; speedup 1.0000x reference)
//
#include <hip/hip_runtime.h>
#include <stdint.h>

typedef __attribute__((ext_vector_type(4))) float    f32x4;
typedef __attribute__((ext_vector_type(8))) _Float16 half8;
typedef __attribute__((ext_vector_type(4))) _Float16 half4;
typedef uint32_t __attribute__((may_alias)) u32a;
typedef unsigned long long u64;

#define MFMA16(a, b, c)    __builtin_amdgcn_mfma_f32_16x16x32_f16(a, b, c, 0, 0, 0)
#define MFMA16K16(a, b, c) __builtin_amdgcn_mfma_f32_16x16x16f16(a, b, c, 0, 0, 0)

#if __has_builtin(__builtin_amdgcn_exp2f)
#define EXP2F(x) __builtin_amdgcn_exp2f(x)
#else
#define EXP2F(x) exp2f(x)
#endif

#define CEXP 0.18033688f  // log2(e)/sqrt(64) — folded into Q at projection time

// read 8 halfs from a 4B-aligned LDS address (odd strides break 16B align)
__device__ inline half8 lds_read8_a4(const _Float16* p) {
    union { u32a u[4]; half8 h; } v;
    const u32a* q = (const u32a*)p;
    v.u[0] = q[0]; v.u[1] = q[1]; v.u[2] = q[2]; v.u[3] = q[3];
    return v.h;
}

// ---------------- fused fp32 -> f16 cast of x + 4 weights ----------------
__global__ __launch_bounds__(256) void cast_all(
    const float* __restrict__ x,  const float* __restrict__ wq,
    const float* __restrict__ wk, const float* __restrict__ wv,
    const float* __restrict__ wo,
    _Float16* __restrict__ xh,  _Float16* __restrict__ wqh,
    _Float16* __restrict__ wkh, _Float16* __restrict__ wvh,
    _Float16* __restrict__ woh) {
    const int NX = 4194304, NW = 1048576;
    int i = (blockIdx.x * 256 + threadIdx.x) * 4;
    const float* src; _Float16* dst; int off;
    if (i < NX) { src = x; dst = xh; off = i; }
    else {
        int j = i - NX; int w = j >> 20; off = j & (NW - 1);
        src = (w == 0) ? wq : (w == 1) ? wk : (w == 2) ? wv : wo;
        dst = (w == 0) ? wqh : (w == 1) ? wkh : (w == 2) ? wvh : woh;
    }
    f32x4 v = *(const f32x4*)(src + off);
    half4 o;
    o.x = (_Float16)v.x; o.y = (_Float16)v.y; o.z = (_Float16)v.z; o.w = (_Float16)v.w;
    *(half4*)(dst + off) = o;
}

// ---------------- GEMM  C[M,N] = A[M,K] * B[N,K]^T  (f16 in, fp32 accum) ----
// Register-prefetch K-loop (R5), XOR slot swizzle (0 conflicts measured).
// MODE 0: BM=64.  C0 = float*, row-major [M,N].
// MODE 3: BM=128. Fused QKV: region 0: Q (prescaled CEXP), 1: K, 2: V^T.
//         Regions 0/1 now use a per-wave stride-66 LDS transpose epilogue
//         (odd dword stride -> <=2-way banks both sides) for coalesced
//         128B half8 stores instead of 64 scattered 2B stores/thread.
#define BN 128
#define BK 64

template <int MODE>
__global__ __launch_bounds__(256) void gemm_bt(const _Float16* __restrict__ A,
                                               const _Float16* __restrict__ B,
                                               void* __restrict__ C0,
                                               void* __restrict__ C1,
                                               void* __restrict__ C2,
                                               int M, int N, int K) {
    constexpr int BM  = (MODE == 3) ? 128 : 64;
    constexpr int MT  = BM / 32;
    constexpr int AIT = BM / 32;
    constexpr int SMEMN = (MODE == 3) ? 16896 : (BM + BN) * BK;  // ep needs 4*4224

    __shared__ __attribute__((aligned(16))) _Float16 smem[SMEMN];
    _Float16* As = smem;
    _Float16* Bs = smem + BM * BK;

    const int tid  = threadIdx.x;
    const int wave = tid >> 6;
    const int lane = tid & 63;
    const int l16  = lane & 15;
    const int quad = lane >> 4;
    const int m0 = blockIdx.y * BM;
    const int n0 = blockIdx.x * BN;
    const int wm = (wave >> 1) * (BM / 2);
    const int wn = (wave & 1) * 64;

    const int srow = tid >> 3;              // 0..31 (+32*i)
    const int g8   = tid & 7;               // global chunk this thread carries
    const int slot = g8 ^ (srow & 7);       // LDS slot

    const _Float16* Ap = A + (size_t)(m0 + srow) * K + g8 * 8;
    const _Float16* Bp = B + (size_t)(n0 + srow) * K + g8 * 8;

    f32x4 acc[MT][4];
#pragma unroll
    for (int i = 0; i < MT; i++)
#pragma unroll
        for (int j = 0; j < 4; j++) acc[i][j] = (f32x4){0.f, 0.f, 0.f, 0.f};

    half8 ar[AIT], br[4];
#pragma unroll
    for (int i = 0; i < AIT; i++) ar[i] = *(const half8*)(Ap + (size_t)i * 32 * K);
#pragma unroll
    for (int i = 0; i < 4; i++)  br[i] = *(const half8*)(Bp + (size_t)i * 32 * K);

    for (int k0 = 0; k0 < K; k0 += BK) {
        __syncthreads();  // prior iter's frag reads complete
#pragma unroll
        for (int i = 0; i < AIT; i++)
            *(half8*)(As + (i * 32 + srow) * 64 + slot * 8) = ar[i];
#pragma unroll
        for (int i = 0; i < 4; i++)
            *(half8*)(Bs + (i * 32 + srow) * 64 + slot * 8) = br[i];
        __syncthreads();

        int k2 = k0 + BK; if (k2 == K) k2 = 0;
#pragma unroll
        for (int i = 0; i < AIT; i++) ar[i] = *(const half8*)(Ap + (size_t)i * 32 * K + k2);
#pragma unroll
        for (int i = 0; i < 4; i++)  br[i] = *(const half8*)(Bp + (size_t)i * 32 * K + k2);

#pragma unroll
        for (int kk = 0; kk < 2; kk++) {
            half8 af[MT], bf[4];
#pragma unroll
            for (int mt = 0; mt < MT; mt++) {
                int row = wm + mt * 16 + l16;
                af[mt] = *(const half8*)(As + row * 64 + ((quad + 4 * kk) ^ (row & 7)) * 8);
            }
#pragma unroll
            for (int nt = 0; nt < 4; nt++) {
                int row = wn + nt * 16 + l16;
                bf[nt] = *(const half8*)(Bs + row * 64 + ((quad + 4 * kk) ^ (row & 7)) * 8);
            }
#pragma unroll
            for (int mt = 0; mt < MT; mt++)
#pragma unroll
                for (int nt = 0; nt < 4; nt++)
                    acc[mt][nt] = MFMA16(af[mt], bf[nt], acc[mt][nt]);
        }
    }

    // C/D layout: row = quad*4 + reg, col = l16
    if (MODE == 0) {
        float* C = (float*)C0;
#pragma unroll
        for (int mt = 0; mt < MT; mt++)
#pragma unroll
            for (int r = 0; r < 4; r++) {
                int row = m0 + wm + mt * 16 + quad * 4 + r;
                float* Crow = C + (size_t)row * N + n0 + wn + l16;
#pragma unroll
                for (int nt = 0; nt < 4; nt++) Crow[nt * 16] = acc[mt][nt][r];
            }
    } else {
        const int region = n0 >> 10;          // block-uniform
        const int nb = (n0 & 1023) + wn;      // 64-aligned
        if (region < 2) {
            // coalesced epilogue: per-wave [64 s][64 d] LDS transpose, stride 66
            _Float16* C = (region == 0) ? (_Float16*)C0 : (_Float16*)C1;
            const float scale = (region == 0) ? CEXP : 1.f;
            __syncthreads();  // K-loop frag reads of smem done
            _Float16* ep = smem + wave * 4224;
#pragma unroll
            for (int mt = 0; mt < MT; mt++)
#pragma unroll
                for (int r = 0; r < 4; r++) {
                    int sr = mt * 16 + quad * 4 + r;
#pragma unroll
                    for (int nt = 0; nt < 4; nt++)
                        ep[sr * 66 + nt * 16 + l16] = (_Float16)(acc[mt][nt][r] * scale);
                }
            // same-wave read-after-write: compiler inserts lgkmcnt, no barrier
            int mgb = m0 + wm;
            int b = mgb >> 11, sbase = mgb & 2047;
            int h = nb >> 6;
            _Float16* Cc = C + ((size_t)b * 16 + h) * 2048 * 64;
#pragma unroll
            for (int j = 0; j < 8; j++) {
                int sr = j * 8 + (lane >> 3);
                half8 v = lds_read8_a4(ep + sr * 66 + (lane & 7) * 8);
                *(half8*)(Cc + (size_t)(sbase + sr) * 64 + (lane & 7) * 8) = v;
            }
        } else {
            // V^T region: per-wave LDS transpose -> coalesced 128B stores
            __syncthreads();
            _Float16* ep = smem + wave * 4096;  // [64 d][64 s]
#pragma unroll
            for (int mt = 0; mt < MT; mt++)
#pragma unroll
                for (int nt = 0; nt < 4; nt++) {
                    int dn = nt * 16 + l16;
                    int sl = (mt * 2 + (quad >> 1)) ^ (dn & 7);
                    union { half4 h; u64 q; } o;
#pragma unroll
                    for (int r = 0; r < 4; r++) o.h[r] = (_Float16)acc[mt][nt][r];
                    *(u64*)(ep + dn * 64 + sl * 8 + (quad & 1) * 4) = o.q;
                }
            __syncthreads();
            int mgb = m0 + wm;
            int b = mgb >> 11, sbase = mgb & 2047;
            int h = nb >> 6;
            _Float16* C = (_Float16*)C2 + ((size_t)b * 16 + h) * 64 * 2048;
#pragma unroll
            for (int j = 0; j < 8; j++) {
                int dn = j * 8 + (lane >> 3);
                int sl = (lane & 7) ^ (dn & 7);
                half8 val = *(const half8*)(ep + dn * 64 + sl * 8);
                *(half8*)(C + (size_t)dn * 2048 + sbase + (lane & 7) * 8) = val;
            }
        }
    }
}

// ---------------- flash attention: LDS-free, barrier-free ----------------
// Q,K: [B*H, S, 64] f16 (Q pre-scaled by CEXP).  Vt: [B*H, 64, S] f16.
// Out: [B, S, 1024] f16.
// Grid (bh=32, qtile=16): same-bh blocks share an XCD (id%8 const) -> each
// XCD L2 serves 4 heads' K/V (2MB < 4MB). 4 waves/block, 32 Q/wave (qt=2).
// K-frags (16 rows x 64B dense) and V^T-frags read DIRECTLY from global:
// no LDS staging, no barriers — waves self-pace, loads pipeline across
// the exp/MFMA phase. S^T=K.Q^T keeps P^T in registers (B-frag of K16 PV).
__global__ __launch_bounds__(256) void attn_kernel(const _Float16* __restrict__ Q,
                                                   const _Float16* __restrict__ Kg,
                                                   const _Float16* __restrict__ Vt,
                                                   _Float16* __restrict__ Oa) {
    const int tid  = threadIdx.x;
    const int wave = tid >> 6;
    const int lane = tid & 63;
    const int l16  = lane & 15;
    const int quad = lane >> 4;
    const int bh = blockIdx.x;
    const int q0 = blockIdx.y * 128 + wave * 32;

    // Q frags (B-side of S^T): [n=query l16][k=(quad+4kk)*8+j]
    half8 qf[2][2];
#pragma unroll
    for (int qt = 0; qt < 2; qt++)
#pragma unroll
        for (int kk = 0; kk < 2; kk++)
            qf[qt][kk] = *(const half8*)(Q + ((size_t)bh * 2048 + q0 + qt * 16 + l16) * 64 +
                                         (quad + 4 * kk) * 8);

    // lane-fixed frag base pointers
    const _Float16* Kb = Kg + (size_t)bh * 2048 * 64 + (size_t)l16 * 64 + quad * 8;
    const _Float16* Vb = Vt + (size_t)bh * 64 * 2048 + (size_t)l16 * 2048 + quad * 4;

    f32x4 lsum4[2];
    f32x4 oacc[2][4];  // [qt][dt]: row=quad*4+r = d, col=l16 = query
#pragma unroll
    for (int qt = 0; qt < 2; qt++) {
        lsum4[qt] = (f32x4){0.f, 0.f, 0.f, 0.f};
#pragma unroll
        for (int dt = 0; dt < 4; dt++) oacc[qt][dt] = (f32x4){0.f, 0.f, 0.f, 0.f};
    }

    for (int kt = 0; kt < 2048; kt += 64) {
        // ---- load all K-frags (8 b128) and V-frags (16 b64) for this tile ----
        half8 kf[4][2];
#pragma unroll
        for (int nt = 0; nt < 4; nt++) {
            const _Float16* kr = Kb + (size_t)(kt + nt * 16) * 64;
            kf[nt][0] = *(const half8*)(kr);
            kf[nt][1] = *(const half8*)(kr + 32);
        }
        half4 vf[4][4];
#pragma unroll
        for (int dt = 0; dt < 4; dt++)
#pragma unroll
            for (int nt = 0; nt < 4; nt++)
                vf[dt][nt] = *(const half4*)(Vb + (size_t)dt * 16 * 2048 + kt + nt * 16);

        // ---- S^T = K.Q^T : key = nt*16+quad*4+r, query = l16 ----
        f32x4 sc4[2][4];
#pragma unroll
        for (int nt = 0; nt < 4; nt++)
#pragma unroll
            for (int qt = 0; qt < 2; qt++) {
                f32x4 s = (f32x4){0.f, 0.f, 0.f, 0.f};
                s = MFMA16(kf[nt][0], qf[qt][0], s);
                s = MFMA16(kf[nt][1], qf[qt][1], s);
                sc4[qt][nt] = s;
            }

        // ---- exp2 (scale pre-folded into Q) + per-lane partial sums ----
        half4 ph[2][4];
#pragma unroll
        for (int qt = 0; qt < 2; qt++)
#pragma unroll
            for (int nt = 0; nt < 4; nt++) {
                half4 pk;
#pragma unroll
                for (int r = 0; r < 4; r++) {
                    float pe = EXP2F(sc4[qt][nt][r]);
                    lsum4[qt][r] += pe;
                    pk[r] = (_Float16)pe;
                }
                ph[qt][nt] = pk;
            }

        // ---- O^T += V^T . P^T : A = V-frag, B = P^T in regs ----
#pragma unroll
        for (int nt = 0; nt < 4; nt++)
#pragma unroll
            for (int dt = 0; dt < 4; dt++)
#pragma unroll
                for (int qt = 0; qt < 2; qt++)
                    oacc[qt][dt] = MFMA16K16(vf[dt][nt], ph[qt][nt], oacc[qt][dt]);
    }

    // ---- epilogue: reduce partials cross-quad, normalize, store ----
    const int b = bh >> 4, h = bh & 15;
#pragma unroll
    for (int qt = 0; qt < 2; qt++) {
        float ls = (lsum4[qt][0] + lsum4[qt][1]) + (lsum4[qt][2] + lsum4[qt][3]);
        ls += __shfl_xor(ls, 16);
        ls += __shfl_xor(ls, 32);
        float inv = 1.f / ls;
        int q = q0 + qt * 16 + l16;
        _Float16* orow = Oa + ((size_t)b * 2048 + q) * 1024 + h * 64;
#pragma unroll
        for (int dt = 0; dt < 4; dt++) {
            half4 o;
#pragma unroll
            for (int r = 0; r < 4; r++) o[r] = (_Float16)(oacc[qt][dt][r] * inv);
            *(half4*)(orow + dt * 16 + quad * 4) = o;
        }
    }
}

// ---------------- launch ----------------
extern "C" void kernel_launch(void* const* d_in, const int* in_sizes, int n_in,
                              void* d_out, int out_size, void* d_ws, size_t ws_size,
                              hipStream_t stream) {
    const float* x  = (const float*)d_in[0];
    const float* Wq = (const float*)d_in[1];
    const float* Wk = (const float*)d_in[2];
    const float* Wv = (const float*)d_in[3];
    const float* Wo = (const float*)d_in[4];
    float* out = (float*)d_out;

    const int NX = 2 * 2048 * 1024;  // 4194304
    const int NW = 1024 * 1024;      // 1048576

    _Float16* ws  = (_Float16*)d_ws;
    _Float16* xh  = ws;                 // [4096,1024]
    _Float16* wqh = xh + NX;            // [3072,1024] fused QKV weight
    _Float16* wkh = wqh + NW;
    _Float16* wvh = wkh + NW;
    _Float16* woh = wvh + NW;
    _Float16* Qb  = woh + NW;           // [32,2048,64]  (pre-scaled by CEXP)
    _Float16* Kb  = Qb + NX;
    _Float16* Vtb = Kb + NX;            // [32,64,2048]  V^T
    _Float16* Ab  = Vtb + NX;           // [4096,1024] attn (head-merged)

    cast_all<<<8192, 256, 0, stream>>>(x, Wq, Wk, Wv, Wo, xh, wqh, wkh, wvh, woh);

    gemm_bt<3><<<dim3(3072 / 128, 4096 / 128), 256, 0, stream>>>(
        xh, wqh, Qb, Kb, Vtb, 4096, 3072, 1024);

    attn_kernel<<<dim3(32, 16), 256, 0, stream>>>(Qb, Kb, Vtb, Ab);

    gemm_bt<0><<<dim3(1024 / 128, 4096 / 64), 256, 0, stream>>>(
        Ab, woh, out, nullptr, nullptr, 4096, 1024, 1024);
}

// Round 7
// 197.152 us; speedup vs baseline: 1.5917x; 1.5917x over previous
//
#include <hip/hip_runtime.h>
#include <stdint.h>

typedef __attribute__((ext_vector_type(4))) float    f32x4;
typedef __attribute__((ext_vector_type(8))) _Float16 half8;
typedef __attribute__((ext_vector_type(4))) _Float16 half4;
typedef uint32_t __attribute__((may_alias)) u32a;
typedef unsigned long long u64;

#define MFMA16(a, b, c)    __builtin_amdgcn_mfma_f32_16x16x32_f16(a, b, c, 0, 0, 0)
#define MFMA16K16(a, b, c) __builtin_amdgcn_mfma_f32_16x16x16f16(a, b, c, 0, 0, 0)

#if __has_builtin(__builtin_amdgcn_exp2f)
#define EXP2F(x) __builtin_amdgcn_exp2f(x)
#else
#define EXP2F(x) exp2f(x)
#endif

#define CEXP 0.18033688f  // log2(e)/sqrt(64) — folded into Q at projection time

// read 8 halfs from a 4B-aligned LDS address (odd strides break 16B align)
__device__ inline half8 lds_read8_a4(const _Float16* p) {
    union { u32a u[4]; half8 h; } v;
    const u32a* q = (const u32a*)p;
    v.u[0] = q[0]; v.u[1] = q[1]; v.u[2] = q[2]; v.u[3] = q[3];
    return v.h;
}

// ---------------- fused fp32 -> f16 cast of x + 4 weights ----------------
__global__ __launch_bounds__(256) void cast_all(
    const float* __restrict__ x,  const float* __restrict__ wq,
    const float* __restrict__ wk, const float* __restrict__ wv,
    const float* __restrict__ wo,
    _Float16* __restrict__ xh,  _Float16* __restrict__ wqh,
    _Float16* __restrict__ wkh, _Float16* __restrict__ wvh,
    _Float16* __restrict__ woh) {
    const int NX = 4194304, NW = 1048576;
    int i = (blockIdx.x * 256 + threadIdx.x) * 4;
    const float* src; _Float16* dst; int off;
    if (i < NX) { src = x; dst = xh; off = i; }
    else {
        int j = i - NX; int w = j >> 20; off = j & (NW - 1);
        src = (w == 0) ? wq : (w == 1) ? wk : (w == 2) ? wv : wo;
        dst = (w == 0) ? wqh : (w == 1) ? wkh : (w == 2) ? wvh : woh;
    }
    f32x4 v = *(const f32x4*)(src + off);
    half4 o;
    o.x = (_Float16)v.x; o.y = (_Float16)v.y; o.z = (_Float16)v.z; o.w = (_Float16)v.w;
    *(half4*)(dst + off) = o;
}

// ---------------- GEMM  C[M,N] = A[M,K] * B[N,K]^T  (f16 in, fp32 accum) ----
// BK=32, LDS double-buffered, ONE barrier per K-iter, register prefetch:
// next tile's global loads issue right after the barrier and ride across the
// whole compute phase (consumed by next iter's ds_write — vmcnt waits there,
// not at the barrier; barrier drains lgkm only).
// Swizzle: chunk c of a 4-chunk (8-half) row stored at slot c ^ ((row>>1)&3);
// frag read of chunk quad at slot quad ^ ((l16>>1)&3): 2-way max both sides.
// MODE 0: BM=64.  C0 = float*, row-major [M,N].
// MODE 3: BM=128. Fused QKV: region 0: Q (prescaled CEXP), 1: K, 2: V^T.
#define BN 128
#define BK 32

template <int MODE>
__global__ __launch_bounds__(256) void gemm_bt(const _Float16* __restrict__ A,
                                               const _Float16* __restrict__ B,
                                               void* __restrict__ C0,
                                               void* __restrict__ C1,
                                               void* __restrict__ C2,
                                               int M, int N, int K) {
    constexpr int BM  = (MODE == 3) ? 128 : 64;
    constexpr int MT  = BM / 32;
    constexpr int ANL = BM / 64;                 // A staging loads per thread
    constexpr int STG = (BM + BN) * BK;          // halfs per dbuf stage
    constexpr int SMEMN = (MODE == 3) ? 16896 : 2 * STG;  // MODE3 ep needs 4*4224

    __shared__ __attribute__((aligned(16))) _Float16 smem[SMEMN];

    const int tid  = threadIdx.x;
    const int wave = tid >> 6;
    const int lane = tid & 63;
    const int l16  = lane & 15;
    const int quad = lane >> 4;
    const int m0 = blockIdx.y * BM;
    const int n0 = blockIdx.x * BN;
    const int wm = (wave >> 1) * (BM / 2);
    const int wn = (wave & 1) * 64;

    const int srow = tid >> 2;                    // 0..63 (+64*i)
    const int c4   = tid & 3;                     // chunk this thread carries
    const int slot = c4 ^ ((srow >> 1) & 3);      // (i*64>>1)&3 == 0

    const _Float16* Ap = A + (size_t)(m0 + srow) * K + c4 * 8;
    const _Float16* Bp = B + (size_t)(n0 + srow) * K + c4 * 8;

    f32x4 acc[MT][4];
#pragma unroll
    for (int i = 0; i < MT; i++)
#pragma unroll
        for (int j = 0; j < 4; j++) acc[i][j] = (f32x4){0.f, 0.f, 0.f, 0.f};

    // prefetch tile 0
    half8 ar[ANL], br[2];
#pragma unroll
    for (int i = 0; i < ANL; i++) ar[i] = *(const half8*)(Ap + (size_t)i * 64 * K);
#pragma unroll
    for (int i = 0; i < 2; i++)   br[i] = *(const half8*)(Bp + (size_t)i * 64 * K);

    const int rslotA = (l16 >> 1) & 3;  // frag-read slot xor bits

    for (int k0 = 0; k0 < K; k0 += BK) {
        const int p = (k0 >> 5) & 1;
        _Float16* As = smem + p * STG;
        _Float16* Bs = As + BM * BK;
#pragma unroll
        for (int i = 0; i < ANL; i++)
            *(half8*)(As + (i * 64 + srow) * BK + slot * 8) = ar[i];
#pragma unroll
        for (int i = 0; i < 2; i++)
            *(half8*)(Bs + (i * 64 + srow) * BK + slot * 8) = br[i];
        __syncthreads();  // single barrier: lgkm drain only

        int k2 = k0 + BK; if (k2 == K) k2 = 0;  // wrap: harmless reload
#pragma unroll
        for (int i = 0; i < ANL; i++) ar[i] = *(const half8*)(Ap + (size_t)i * 64 * K + k2);
#pragma unroll
        for (int i = 0; i < 2; i++)   br[i] = *(const half8*)(Bp + (size_t)i * 64 * K + k2);

        half8 af[MT], bf[4];
#pragma unroll
        for (int mt = 0; mt < MT; mt++)
            af[mt] = *(const half8*)(As + (wm + mt * 16 + l16) * BK + (quad ^ rslotA) * 8);
#pragma unroll
        for (int nt = 0; nt < 4; nt++)
            bf[nt] = *(const half8*)(Bs + (wn + nt * 16 + l16) * BK + (quad ^ rslotA) * 8);
#pragma unroll
        for (int mt = 0; mt < MT; mt++)
#pragma unroll
            for (int nt = 0; nt < 4; nt++)
                acc[mt][nt] = MFMA16(af[mt], bf[nt], acc[mt][nt]);
    }

    // C/D layout: row = quad*4 + reg, col = l16
    if (MODE == 0) {
        float* C = (float*)C0;
#pragma unroll
        for (int mt = 0; mt < MT; mt++)
#pragma unroll
            for (int r = 0; r < 4; r++) {
                int row = m0 + wm + mt * 16 + quad * 4 + r;
                float* Crow = C + (size_t)row * N + n0 + wn + l16;
#pragma unroll
                for (int nt = 0; nt < 4; nt++) Crow[nt * 16] = acc[mt][nt][r];
            }
    } else {
        const int region = n0 >> 10;          // block-uniform
        const int nb = (n0 & 1023) + wn;      // 64-aligned
        if (region < 2) {
            // coalesced epilogue: per-wave [64 s][64 d] LDS transpose, stride 66
            _Float16* C = (region == 0) ? (_Float16*)C0 : (_Float16*)C1;
            const float scale = (region == 0) ? CEXP : 1.f;
            __syncthreads();  // K-loop frag reads of smem done
            _Float16* ep = smem + wave * 4224;
#pragma unroll
            for (int mt = 0; mt < MT; mt++)
#pragma unroll
                for (int r = 0; r < 4; r++) {
                    int sr = mt * 16 + quad * 4 + r;
#pragma unroll
                    for (int nt = 0; nt < 4; nt++)
                        ep[sr * 66 + nt * 16 + l16] = (_Float16)(acc[mt][nt][r] * scale);
                }
            int mgb = m0 + wm;
            int b = mgb >> 11, sbase = mgb & 2047;
            int h = nb >> 6;
            _Float16* Cc = C + ((size_t)b * 16 + h) * 2048 * 64;
#pragma unroll
            for (int j = 0; j < 8; j++) {
                int sr = j * 8 + (lane >> 3);
                half8 v = lds_read8_a4(ep + sr * 66 + (lane & 7) * 8);
                *(half8*)(Cc + (size_t)(sbase + sr) * 64 + (lane & 7) * 8) = v;
            }
        } else {
            // V^T region: per-wave LDS transpose -> coalesced 128B stores
            __syncthreads();
            _Float16* ep = smem + wave * 4096;  // [64 d][64 s]
#pragma unroll
            for (int mt = 0; mt < MT; mt++)
#pragma unroll
                for (int nt = 0; nt < 4; nt++) {
                    int dn = nt * 16 + l16;
                    int sl = (mt * 2 + (quad >> 1)) ^ (dn & 7);
                    union { half4 h; u64 q; } o;
#pragma unroll
                    for (int r = 0; r < 4; r++) o.h[r] = (_Float16)acc[mt][nt][r];
                    *(u64*)(ep + dn * 64 + sl * 8 + (quad & 1) * 4) = o.q;
                }
            __syncthreads();
            int mgb = m0 + wm;
            int b = mgb >> 11, sbase = mgb & 2047;
            int h = nb >> 6;
            _Float16* C = (_Float16*)C2 + ((size_t)b * 16 + h) * 64 * 2048;
#pragma unroll
            for (int j = 0; j < 8; j++) {
                int dn = j * 8 + (lane >> 3);
                int sl = (lane & 7) ^ (dn & 7);
                half8 val = *(const half8*)(ep + dn * 64 + sl * 8);
                *(half8*)(C + (size_t)dn * 2048 + sbase + (lane & 7) * 8) = val;
            }
        }
    }
}

// ---------------- flash attention (transposed-score form) ----------------
// Q,K: [B*H, S, 64] f16 (Q pre-scaled by CEXP).  Vt: [B*H, 64, S] f16.
// Out: [B, S, 1024] f16.
// R4 tile shape (4 waves, 128 Q/block, qt=2 -> 32 Q/wave) + R5 pipelining:
// LDS double-buffer, ONE barrier/key-tile, next tile's K/V loads issued
// right after the barrier ride across the whole compute phase.
// K staged with XOR slot swizzle, V at padded stride 68 (0 conflicts in R4).
__global__ __launch_bounds__(256) void attn_kernel(const _Float16* __restrict__ Q,
                                                   const _Float16* __restrict__ Kg,
                                                   const _Float16* __restrict__ Vt,
                                                   _Float16* __restrict__ Oa) {
    __shared__ __attribute__((aligned(16))) _Float16 Ks[2][64 * 64];
    __shared__ __attribute__((aligned(16))) _Float16 Vs[2][64 * 68];  // padded [d][s]

    const int tid  = threadIdx.x;
    const int wave = tid >> 6;
    const int lane = tid & 63;
    const int l16  = lane & 15;
    const int quad = lane >> 4;
    const int bh = blockIdx.y;
    const int q0 = blockIdx.x * 128 + wave * 32;

    // Q frags (B-side of S^T): [n=query l16][k=(quad+4kk)*8+j]
    half8 qf[2][2];
#pragma unroll
    for (int qt = 0; qt < 2; qt++)
#pragma unroll
        for (int kk = 0; kk < 2; kk++)
            qf[qt][kk] = *(const half8*)(Q + ((size_t)bh * 2048 + q0 + qt * 16 + l16) * 64 +
                                         (quad + 4 * kk) * 8);

    const int srow  = tid >> 3;               // 0..31 (+32)
    const int g8    = tid & 7;                // source chunk
    const int kslot = g8 ^ (srow & 7);        // K slot

    const _Float16* kp = Kg + (size_t)bh * 2048 * 64 + (size_t)srow * 64 + g8 * 8;
    const _Float16* vp = Vt + (size_t)bh * 64 * 2048 + (size_t)srow * 2048 + g8 * 8;

    f32x4 lsum4[2];
    f32x4 oacc[2][4];  // [qt][dt]: row=quad*4+r = d, col=l16 = query
#pragma unroll
    for (int qt = 0; qt < 2; qt++) {
        lsum4[qt] = (f32x4){0.f, 0.f, 0.f, 0.f};
#pragma unroll
        for (int dt = 0; dt < 4; dt++) oacc[qt][dt] = (f32x4){0.f, 0.f, 0.f, 0.f};
    }

    // prefetch tile 0
    half8 kr0 = *(const half8*)(kp);
    half8 kr1 = *(const half8*)(kp + 32 * 64);
    half8 vr0 = *(const half8*)(vp);
    half8 vr1 = *(const half8*)(vp + 32 * 2048);

    for (int kt = 0; kt < 2048; kt += 64) {
        const int p = (kt >> 6) & 1;
        // stage prefetched regs (vmcnt waits land here; loads had the whole
        // previous compute phase to complete)
        *(half8*)(&Ks[p][srow * 64 + kslot * 8]) = kr0;
        *(half8*)(&Ks[p][(srow + 32) * 64 + kslot * 8]) = kr1;
        {
            union { half8 h; u64 q[2]; } u0, u1;
            u0.h = vr0; u1.h = vr1;
            _Float16* vd0 = &Vs[p][srow * 68 + g8 * 8];
            _Float16* vd1 = &Vs[p][(srow + 32) * 68 + g8 * 8];
            *(u64*)(vd0) = u0.q[0]; *(u64*)(vd0 + 4) = u0.q[1];
            *(u64*)(vd1) = u1.q[0]; *(u64*)(vd1 + 4) = u1.q[1];
        }
        __syncthreads();  // single barrier per tile (lgkm drain only)

        // issue next tile's loads; they ride across this compute phase
        {
            int kt2 = (kt + 64) & 2047;
            kr0 = *(const half8*)(kp + (size_t)kt2 * 64);
            kr1 = *(const half8*)(kp + (size_t)(kt2 + 32) * 64);
            vr0 = *(const half8*)(vp + kt2);
            vr1 = *(const half8*)(vp + 32 * 2048 + kt2);
        }

        // ---- S^T = K.Q^T : key = nt*16+quad*4+r, query = l16 ----
        f32x4 sc4[2][4];
#pragma unroll
        for (int nt = 0; nt < 4; nt++) {
            int row = nt * 16 + l16;
            half8 kf0 = *(const half8*)(&Ks[p][row * 64 + (quad ^ (row & 7)) * 8]);
            half8 kf1 = *(const half8*)(&Ks[p][row * 64 + ((quad + 4) ^ (row & 7)) * 8]);
#pragma unroll
            for (int qt = 0; qt < 2; qt++) {
                f32x4 s = (f32x4){0.f, 0.f, 0.f, 0.f};
                s = MFMA16(kf0, qf[qt][0], s);
                s = MFMA16(kf1, qf[qt][1], s);
                sc4[qt][nt] = s;
            }
        }

        // ---- exp2 (scale pre-folded into Q) + per-lane partial sums ----
        half4 ph[2][4];
#pragma unroll
        for (int qt = 0; qt < 2; qt++)
#pragma unroll
            for (int nt = 0; nt < 4; nt++) {
                half4 pk;
#pragma unroll
                for (int r = 0; r < 4; r++) {
                    float pe = EXP2F(sc4[qt][nt][r]);
                    lsum4[qt][r] += pe;
                    pk[r] = (_Float16)pe;
                }
                ph[qt][nt] = pk;
            }

        // ---- O^T += V^T . P^T : A = V-frag (padded b64), B = P^T in regs ----
#pragma unroll
        for (int nt = 0; nt < 4; nt++) {
#pragma unroll
            for (int dt = 0; dt < 4; dt++) {
                int row = dt * 16 + l16;
                half4 vf = *(const half4*)(&Vs[p][row * 68 + nt * 16 + quad * 4]);
#pragma unroll
                for (int qt = 0; qt < 2; qt++)
                    oacc[qt][dt] = MFMA16K16(vf, ph[qt][nt], oacc[qt][dt]);
            }
        }
    }

    // ---- epilogue: reduce partials cross-quad, normalize, store ----
    const int b = bh >> 4, h = bh & 15;
#pragma unroll
    for (int qt = 0; qt < 2; qt++) {
        float ls = (lsum4[qt][0] + lsum4[qt][1]) + (lsum4[qt][2] + lsum4[qt][3]);
        ls += __shfl_xor(ls, 16);
        ls += __shfl_xor(ls, 32);
        float inv = 1.f / ls;
        int q = q0 + qt * 16 + l16;
        _Float16* orow = Oa + ((size_t)b * 2048 + q) * 1024 + h * 64;
#pragma unroll
        for (int dt = 0; dt < 4; dt++) {
            half4 o;
#pragma unroll
            for (int r = 0; r < 4; r++) o[r] = (_Float16)(oacc[qt][dt][r] * inv);
            *(half4*)(orow + dt * 16 + quad * 4) = o;
        }
    }
}

// ---------------- launch ----------------
extern "C" void kernel_launch(void* const* d_in, const int* in_sizes, int n_in,
                              void* d_out, int out_size, void* d_ws, size_t ws_size,
                              hipStream_t stream) {
    const float* x  = (const float*)d_in[0];
    const float* Wq = (const float*)d_in[1];
    const float* Wk = (const float*)d_in[2];
    const float* Wv = (const float*)d_in[3];
    const float* Wo = (const float*)d_in[4];
    float* out = (float*)d_out;

    const int NX = 2 * 2048 * 1024;  // 4194304
    const int NW = 1024 * 1024;      // 1048576

    _Float16* ws  = (_Float16*)d_ws;
    _Float16* xh  = ws;                 // [4096,1024]
    _Float16* wqh = xh + NX;            // [3072,1024] fused QKV weight
    _Float16* wkh = wqh + NW;
    _Float16* wvh = wkh + NW;
    _Float16* woh = wvh + NW;
    _Float16* Qb  = woh + NW;           // [32,2048,64]  (pre-scaled by CEXP)
    _Float16* Kb  = Qb + NX;
    _Float16* Vtb = Kb + NX;            // [32,64,2048]  V^T
    _Float16* Ab  = Vtb + NX;           // [4096,1024] attn (head-merged)

    cast_all<<<8192, 256, 0, stream>>>(x, Wq, Wk, Wv, Wo, xh, wqh, wkh, wvh, woh);

    gemm_bt<3><<<dim3(3072 / 128, 4096 / 128), 256, 0, stream>>>(
        xh, wqh, Qb, Kb, Vtb, 4096, 3072, 1024);

    attn_kernel<<<dim3(16, 32), 256, 0, stream>>>(Qb, Kb, Vtb, Ab);

    gemm_bt<0><<<dim3(1024 / 128, 4096 / 64), 256, 0, stream>>>(
        Ab, woh, out, nullptr, nullptr, 4096, 1024, 1024);
}